// Round 2
// baseline (261.748 us; speedup 1.0000x reference)
//
#include <hip/hip_runtime.h>
#include <hip/hip_cooperative_groups.h>
#include <math.h>

namespace cg = cooperative_groups;

// MoE top-2-of-8: B=1024, I=512, H=2048, O=512, E=8, K=2.
// R10: single cooperative kernel. 256 blocks x 512 thr, 4 phases separated by
// grid.sync(): (0) gating on waves 0-3 while waves 4-7 prestage fc1 W-panel
// chunk 0 into LDS (no dependency); (1) fc1 with per-block ballot-scan slot
// list (R9); (2) fc2 BN=32 / kc=2 (R9); (3) combine. Removes all inter-kernel
// launch boundaries. GEMM core unchanged from R8/R9: contiguous 256B W row
// segments transposed into LDS [n][k] bf16 via k-pair-packed b32 writes,
// per-lane direct global b128 A-frags, 16x16x32 bf16 MFMA.
// Fallback: if hipLaunchCooperativeKernel is rejected, run the R9 4-kernel path.

#define B_TOK 1024
#define I_DIM 512
#define H_DIM 2048
#define O_DIM 512
#define E_NUM 8
#define CAP   1024                       // per-expert slot capacity (max Me)

#define WS_COUNTS   0                    // 8 ints   (written by fc1 nx==0)
#define WS_TOK_E    64                   // [1024][2] int
#define WS_TOK_W    8256                 // [1024][2] float
#define WS_TOK_SLOT 16448                // [1024][2] int (written by fc1 nx==0)
#define WS_XB       65536                // [1024][512] bf16 = 1 MB
#define WS_HB       (WS_XB + 1048576)    // [8*1024][2048] bf16 = 32 MB
#define WS_Y2       (WS_HB + 33554432)   // [2][8192][512] f32 = 32 MB

typedef __attribute__((ext_vector_type(8))) __bf16 bf16x8;
typedef __attribute__((ext_vector_type(4))) __bf16 bf16x4;
typedef __attribute__((ext_vector_type(2))) __bf16 bf16x2;
typedef __attribute__((ext_vector_type(4))) float f32x4;

#define MFMA16 __builtin_amdgcn_mfma_f32_16x16x32_bf16

#define BSTR1 520                        // fc1 LDS row stride (512 + 8 pad)
#define BSTR2 1032                       // fc2 LDS row stride (1024 + 8 pad)
#define SMEM_BS    (64 * BSTR1 * 2)      // 66560 B (fc2 needs 32*1032*2=66048)
#define SMEM_BYTES (SMEM_BS + CAP * 4 + 16)

// ---------------------------------------------------------------------------
__global__ __launch_bounds__(512) void moe_fused(
    const float* __restrict__ x, const float* __restrict__ Wg,
    const float* __restrict__ bg, const float* __restrict__ W1f,
    const float* __restrict__ b1, const float* __restrict__ W2f,
    const float* __restrict__ b2, float* __restrict__ out,
    char* __restrict__ ws)
{
    int*    counts   = (int*)(ws + WS_COUNTS);
    int*    tok_e    = (int*)(ws + WS_TOK_E);
    float*  tok_w    = (float*)(ws + WS_TOK_W);
    int*    tok_slot = (int*)(ws + WS_TOK_SLOT);
    __bf16* xb       = (__bf16*)(ws + WS_XB);
    __bf16* hb       = (__bf16*)(ws + WS_HB);
    float*  y2       = (float*)(ws + WS_Y2);

    __shared__ __align__(16) char smem[SMEM_BYTES];
    __bf16* Bs     = (__bf16*)smem;
    int*    sl_tok = (int*)(smem + SMEM_BS);
    int*    sMe    = (int*)(smem + SMEM_BS + CAP * 4);

    cg::grid_group grid = cg::this_grid();
    const int tid  = threadIdx.x;
    const int lane = tid & 63;
    const int w    = tid >> 6;
    const int bid  = blockIdx.x;
    const int l15  = lane & 15, q = lane >> 4;

    // phase-1 block mapping (needed in phase 0 for the prestage)
    const int e1  = bid >> 5, nx1 = bid & 31;
    const int n01 = nx1 * 64;
    const float* W1 = W1f + (size_t)e1 * (I_DIM * H_DIM);

    // ===== phase 0: gating (waves 0-3) + fc1 chunk-0 prestage (waves 4-7) ==
    if (w < 4) {
        const int t = bid * 4 + w;
        const float4* x4 = (const float4*)(x + (size_t)t * I_DIM);
        float4 va = x4[lane], vb = x4[lane + 64];
        bf16x4 oa, ob;
        oa[0] = (__bf16)va.x; oa[1] = (__bf16)va.y;
        oa[2] = (__bf16)va.z; oa[3] = (__bf16)va.w;
        ob[0] = (__bf16)vb.x; ob[1] = (__bf16)vb.y;
        ob[2] = (__bf16)vb.z; ob[3] = (__bf16)vb.w;
        *(bf16x4*)(xb + (size_t)t * I_DIM + lane * 4) = oa;
        *(bf16x4*)(xb + (size_t)t * I_DIM + 256 + lane * 4) = ob;

        float gacc[8];
#pragma unroll
        for (int e = 0; e < 8; ++e) gacc[e] = 0.f;
        float xv[8] = {va.x, va.y, va.z, va.w, vb.x, vb.y, vb.z, vb.w};
#pragma unroll
        for (int u = 0; u < 8; ++u) {
            int i = (u < 4) ? (lane * 4 + u) : (256 + lane * 4 + u - 4);
            const float4* wr = (const float4*)(Wg + (size_t)i * 8);
            float4 wa = wr[0], wb2 = wr[1];
            gacc[0] = fmaf(xv[u], wa.x, gacc[0]);
            gacc[1] = fmaf(xv[u], wa.y, gacc[1]);
            gacc[2] = fmaf(xv[u], wa.z, gacc[2]);
            gacc[3] = fmaf(xv[u], wa.w, gacc[3]);
            gacc[4] = fmaf(xv[u], wb2.x, gacc[4]);
            gacc[5] = fmaf(xv[u], wb2.y, gacc[5]);
            gacc[6] = fmaf(xv[u], wb2.z, gacc[6]);
            gacc[7] = fmaf(xv[u], wb2.w, gacc[7]);
        }
#pragma unroll
        for (int off = 32; off > 0; off >>= 1)
#pragma unroll
            for (int e = 0; e < 8; ++e)
                gacc[e] += __shfl_xor(gacc[e], off, 64);
        if (lane == 0) {
            float l[8];
#pragma unroll
            for (int e = 0; e < 8; ++e) l[e] = gacc[e] + bg[e];
            int E0 = 0;
            for (int e = 1; e < 8; ++e) if (l[e] > l[E0]) E0 = e;
            int E1 = (E0 == 0) ? 1 : 0;
            for (int e = 0; e < 8; ++e) {
                if (e == E0) continue;
                if (l[e] > l[E1]) E1 = e;
            }
            float w0 = 1.f / (1.f + expf(l[E1] - l[E0]));  // p0/(p0+p1)
            tok_e[t * 2]     = E0;
            tok_e[t * 2 + 1] = E1;
            tok_w[t * 2]     = w0;
            tok_w[t * 2 + 1] = 1.f - w0;
        }
    } else {
        // prestage fc1 chunk 0 (k 0..255): 2048 units / 256 thr = 8 each
#pragma unroll
        for (int i = 0; i < 8; ++i) {
            const int u = (tid - 256) + 256 * i;
            const int p = u >> 4, c4 = u & 15;
            const float* wp = W1 + (size_t)(2 * p) * H_DIM + n01 + c4 * 4;
            float4 r0 = *(const float4*)wp;
            float4 r1 = *(const float4*)(wp + H_DIM);
            const float* f0 = (const float*)&r0;
            const float* f1 = (const float*)&r1;
#pragma unroll
            for (int j = 0; j < 4; ++j) {
                bf16x2 pk;
                pk[0] = (__bf16)f0[j];
                pk[1] = (__bf16)f1[j];
                *(bf16x2*)&Bs[(size_t)(c4 * 4 + j) * BSTR1 + 2 * p] = pk;
            }
        }
    }
    grid.sync();

    // ====================== phase 1: fc1 (BN=64, K=512) ====================
    {
        // wave-0 ballot-scan: slot list for expert e1 (token-order ranks,
        // identical across the expert's 32 blocks). nx==0 publishes globals.
        if (w == 0) {
            int cnt = 0;
#pragma unroll
            for (int b = 0; b < 2; ++b) {
                int vals[16];
#pragma unroll
                for (int c = 0; c < 16; ++c)
                    vals[c] = tok_e[(b * 16 + c) * 64 + lane];
#pragma unroll
                for (int c = 0; c < 16; ++c) {
                    const int gidx = (b * 16 + c) * 64 + lane;
                    const bool hit = (vals[c] == e1);
                    const unsigned long long mk = __ballot(hit);
                    if (hit) {
                        const int pos = cnt + __popcll(mk & ((1ull << lane) - 1));
                        sl_tok[pos] = gidx >> 1;
                        if (nx1 == 0) tok_slot[gidx] = e1 * CAP + pos;
                    }
                    cnt += __popcll(mk);
                }
            }
            if (lane == 0) {
                sMe[0] = cnt;
                if (nx1 == 0) counts[e1] = cnt;
            }
        }
        __syncthreads();                    // scan results ready (chunk 0 already is)
        const int Me  = sMe[0];
        const int off = e1 * CAP;

        // stage chunk 1 (k 256..511): 2048 units / 512 thr = 4 each
#pragma unroll
        for (int i = 0; i < 4; ++i) {
            const int u = tid + 512 * i;
            const int p = u >> 4, c4 = u & 15;
            const float* wp = W1 + (size_t)(256 + 2 * p) * H_DIM + n01 + c4 * 4;
            float4 r0 = *(const float4*)wp;
            float4 r1 = *(const float4*)(wp + H_DIM);
            const float* f0 = (const float*)&r0;
            const float* f1 = (const float*)&r1;
#pragma unroll
            for (int j = 0; j < 4; ++j) {
                bf16x2 pk;
                pk[0] = (__bf16)f0[j];
                pk[1] = (__bf16)f1[j];
                *(bf16x2*)&Bs[(size_t)(c4 * 4 + j) * BSTR1 + 256 + 2 * p] = pk;
            }
        }

        auto aptrF = [&](int m0, const __bf16*& a0, const __bf16*& a1) {
            int mA = m0 + l15;      if (mA >= Me) mA = Me - 1;
            int mB = m0 + 16 + l15; if (mB >= Me) mB = Me - 1;
            a0 = xb + (size_t)sl_tok[mA] * I_DIM + q * 8;
            a1 = xb + (size_t)sl_tok[mB] * I_DIM + q * 8;
        };
        auto computeF = [&](const __bf16* a0, const __bf16* a1,
                            f32x4 (&acc)[2][4], int ks0, int ks1) {
#pragma unroll 4
            for (int ks = ks0; ks < ks1; ++ks) {
                bf16x8 af0 = *(const bf16x8*)(a0 + ks * 32);
                bf16x8 af1 = *(const bf16x8*)(a1 + ks * 32);
#pragma unroll
                for (int jj = 0; jj < 4; ++jj) {
                    bf16x8 bf = *(const bf16x8*)
                        &Bs[(size_t)(jj * 16 + l15) * BSTR1 + ks * 32 + q * 8];
                    acc[0][jj] = MFMA16(af0, bf, acc[0][jj], 0, 0, 0);
                    acc[1][jj] = MFMA16(af1, bf, acc[1][jj], 0, 0, 0);
                }
            }
        };
        // epilogue: C/D layout col=l15, row=q*4+reg (verified m89)
        auto epiF = [&](int m0, f32x4 (&acc)[2][4]) {
#pragma unroll
            for (int jj = 0; jj < 4; ++jj) {
                const int gn = n01 + jj * 16 + l15;
                const float bv = b1[e1 * H_DIM + gn];
#pragma unroll
                for (int i2 = 0; i2 < 2; ++i2)
#pragma unroll
                    for (int r = 0; r < 4; ++r) {
                        int m = m0 + i2 * 16 + q * 4 + r;
                        if (m < Me) {
                            float v = acc[i2][jj][r] + bv;
                            hb[(size_t)(off + m) * H_DIM + gn] =
                                (__bf16)fmaxf(v, 0.f);
                        }
                    }
            }
        };

        const bool act0 = (w * 32 < Me);
        f32x4 acc[2][4] = {};
        const __bf16 *a0 = nullptr, *a1 = nullptr;
        if (act0) {
            aptrF(w * 32, a0, a1);
            computeF(a0, a1, acc, 0, 8);   // chunk-0 compute overlaps chunk-1 stage
        }
        __syncthreads();                   // chunk 1 resident
        if (act0) {
            computeF(a0, a1, acc, 8, 16);
            epiF(w * 32, acc);
        }
        for (int m0 = w * 32 + 256; m0 < Me; m0 += 256) {  // overflow tiles
            f32x4 acc2[2][4] = {};
            aptrF(m0, a0, a1);
            computeF(a0, a1, acc2, 0, 16);
            epiF(m0, acc2);
        }
    }
    grid.sync();

    // ================= phase 2: fc2 (BN=32, K=1024, kc=2) ==================
    {
        const int e  = bid >> 5, kc = (bid >> 4) & 1, nx = bid & 15;
        const int Me = counts[e];
        const int off = e * CAP;
        const int k0 = kc * 1024;
        const int n0 = nx * 32;
        const float* W2 = W2f + (size_t)e * (H_DIM * O_DIM);

        auto stage2 = [&](int ch) {
            const int kb = k0 + ch * 256;
#pragma unroll
            for (int i = 0; i < 2; ++i) {       // 1024 units / 512 thr
                const int u = tid + 512 * i;
                const int p = u >> 3, c4 = u & 7;
                const float* wp = W2 + (size_t)(kb + 2 * p) * O_DIM + n0 + c4 * 4;
                float4 r0 = *(const float4*)wp;
                float4 r1 = *(const float4*)(wp + O_DIM);
                const float* f0 = (const float*)&r0;
                const float* f1 = (const float*)&r1;
#pragma unroll
                for (int j = 0; j < 4; ++j) {
                    bf16x2 pk;
                    pk[0] = (__bf16)f0[j];
                    pk[1] = (__bf16)f1[j];
                    *(bf16x2*)&Bs[(size_t)(c4 * 4 + j) * BSTR2 + ch * 256 + 2 * p] = pk;
                }
            }
        };
        stage2(0);
        __syncthreads();
        stage2(1); stage2(2); stage2(3);       // overlap with chunk-0 compute

        auto aptr2 = [&](int m0, const __bf16*& a0, const __bf16*& a1) {
            int mA = m0 + l15;      if (mA >= Me) mA = Me - 1;
            int mB = m0 + 16 + l15; if (mB >= Me) mB = Me - 1;
            a0 = hb + (size_t)(off + mA) * H_DIM + k0 + q * 8;
            a1 = hb + (size_t)(off + mB) * H_DIM + k0 + q * 8;
        };
        auto compute2 = [&](const __bf16* a0, const __bf16* a1,
                            f32x4 (&acc)[2][2], int ks0, int ks1) {
#pragma unroll 4
            for (int ks = ks0; ks < ks1; ++ks) {
                bf16x8 af0 = *(const bf16x8*)(a0 + ks * 32);
                bf16x8 af1 = *(const bf16x8*)(a1 + ks * 32);
#pragma unroll
                for (int jj = 0; jj < 2; ++jj) {
                    bf16x8 bf = *(const bf16x8*)
                        &Bs[(size_t)(jj * 16 + l15) * BSTR2 + ks * 32 + q * 8];
                    acc[0][jj] = MFMA16(af0, bf, acc[0][jj], 0, 0, 0);
                    acc[1][jj] = MFMA16(af1, bf, acc[1][jj], 0, 0, 0);
                }
            }
        };
        auto epi2 = [&](int m0, f32x4 (&acc)[2][2]) {
#pragma unroll
            for (int jj = 0; jj < 2; ++jj) {
                const int gn = n0 + jj * 16 + l15;
#pragma unroll
                for (int i2 = 0; i2 < 2; ++i2)
#pragma unroll
                    for (int r = 0; r < 4; ++r) {
                        int m = m0 + i2 * 16 + q * 4 + r;
                        if (m < Me)
                            y2[((size_t)kc * (E_NUM * CAP) + off + m) * O_DIM + gn] =
                                acc[i2][jj][r];
                    }
            }
        };

        const bool act0 = (w * 32 < Me);
        f32x4 acc[2][2] = {};
        const __bf16 *a0 = nullptr, *a1 = nullptr;
        if (act0) {
            aptr2(w * 32, a0, a1);
            compute2(a0, a1, acc, 0, 8);
        }
        __syncthreads();                   // chunks 1-3 resident
        if (act0) {
            compute2(a0, a1, acc, 8, 32);
            epi2(w * 32, acc);
        }
        for (int m0 = w * 32 + 256; m0 < Me; m0 += 256) {  // overflow tiles
            f32x4 acc2[2][2] = {};
            aptr2(m0, a0, a1);
            compute2(a0, a1, acc2, 0, 32);
            epi2(m0, acc2);
        }
    }
    grid.sync();

    // ========================= phase 3: combine ============================
    {
        const int idx = bid * 512 + tid;       // B*O/4 = 131072 units
        const int t = idx >> 7;
        const int c = (idx & 127) * 4;
        float4 sum = {0.f, 0.f, 0.f, 0.f};
#pragma unroll
        for (int k = 0; k < 2; ++k) {
            const int s = tok_slot[t * 2 + k];
            const int e = tok_e[t * 2 + k];
            const float wgt = tok_w[t * 2 + k];
            float4 a = *(const float4*)(b2 + (size_t)e * O_DIM + c);
#pragma unroll
            for (int kc = 0; kc < 2; ++kc) {
                float4 v = *(const float4*)
                    (y2 + ((size_t)kc * (E_NUM * CAP) + s) * O_DIM + c);
                a.x += v.x; a.y += v.y; a.z += v.z; a.w += v.w;
            }
            sum.x += wgt * a.x; sum.y += wgt * a.y;
            sum.z += wgt * a.z; sum.w += wgt * a.w;
        }
        *(float4*)(out + (size_t)t * O_DIM + c) = sum;
    }
}

// ===========================================================================
// Fallback path (R9, non-cooperative) in case the coop launch is rejected.
// ===========================================================================
__global__ __launch_bounds__(256) void gating_kernel(
    const float* __restrict__ x, const float* __restrict__ Wg,
    const float* __restrict__ bg, __bf16* __restrict__ xb,
    int* __restrict__ tok_e, float* __restrict__ tok_w)
{
    const int lane = threadIdx.x & 63;
    const int t = blockIdx.x * 4 + (threadIdx.x >> 6);
    const float4* x4 = (const float4*)(x + (size_t)t * I_DIM);
    float4 va = x4[lane], vb = x4[lane + 64];
    bf16x4 oa, ob;
    oa[0] = (__bf16)va.x; oa[1] = (__bf16)va.y;
    oa[2] = (__bf16)va.z; oa[3] = (__bf16)va.w;
    ob[0] = (__bf16)vb.x; ob[1] = (__bf16)vb.y;
    ob[2] = (__bf16)vb.z; ob[3] = (__bf16)vb.w;
    *(bf16x4*)(xb + (size_t)t * I_DIM + lane * 4) = oa;
    *(bf16x4*)(xb + (size_t)t * I_DIM + 256 + lane * 4) = ob;
    float acc[8];
#pragma unroll
    for (int e = 0; e < 8; ++e) acc[e] = 0.f;
    float xv[8] = {va.x, va.y, va.z, va.w, vb.x, vb.y, vb.z, vb.w};
#pragma unroll
    for (int u = 0; u < 8; ++u) {
        int i = (u < 4) ? (lane * 4 + u) : (256 + lane * 4 + u - 4);
        const float4* wr = (const float4*)(Wg + (size_t)i * 8);
        float4 wa = wr[0], wb2 = wr[1];
        acc[0] = fmaf(xv[u], wa.x, acc[0]);
        acc[1] = fmaf(xv[u], wa.y, acc[1]);
        acc[2] = fmaf(xv[u], wa.z, acc[2]);
        acc[3] = fmaf(xv[u], wa.w, acc[3]);
        acc[4] = fmaf(xv[u], wb2.x, acc[4]);
        acc[5] = fmaf(xv[u], wb2.y, acc[5]);
        acc[6] = fmaf(xv[u], wb2.z, acc[6]);
        acc[7] = fmaf(xv[u], wb2.w, acc[7]);
    }
#pragma unroll
    for (int off = 32; off > 0; off >>= 1)
#pragma unroll
        for (int e = 0; e < 8; ++e)
            acc[e] += __shfl_xor(acc[e], off, 64);
    if (lane == 0) {
        float l[8];
#pragma unroll
        for (int e = 0; e < 8; ++e) l[e] = acc[e] + bg[e];
        int e0 = 0;
        for (int e = 1; e < 8; ++e) if (l[e] > l[e0]) e0 = e;
        int e1 = (e0 == 0) ? 1 : 0;
        for (int e = 0; e < 8; ++e) {
            if (e == e0) continue;
            if (l[e] > l[e1]) e1 = e;
        }
        float w0 = 1.f / (1.f + expf(l[e1] - l[e0]));
        tok_e[t * 2]     = e0;
        tok_e[t * 2 + 1] = e1;
        tok_w[t * 2]     = w0;
        tok_w[t * 2 + 1] = 1.f - w0;
    }
}

template <bool IS_FC1>
__global__ __launch_bounds__(512) void moe_gemm(
    const __bf16* __restrict__ A, const float* __restrict__ Wf,
    const float* __restrict__ bias,
    int* __restrict__ counts, const int* __restrict__ tok_e,
    int* __restrict__ tok_slot,
    __bf16* __restrict__ hb, float* __restrict__ y2)
{
    constexpr int BN    = IS_FC1 ? 64 : 32;
    constexpr int KSPAN = IS_FC1 ? 512 : 1024;
    constexpr int BSTR  = KSPAN + 8;
    constexpr int NCH   = KSPAN / 256;
    constexpr int JN    = BN / 16;
    constexpr int C4N   = BN / 4;
    constexpr int NW    = IS_FC1 ? H_DIM : O_DIM;
    constexpr int ASTR  = IS_FC1 ? I_DIM : H_DIM;

    const int e  = blockIdx.z;
    const int kc = IS_FC1 ? 0 : (int)blockIdx.y;
    const int k0 = kc * KSPAN;
    const int n0 = blockIdx.x * BN;
    const int off = e * CAP;
    const float* W = Wf + (size_t)e * (IS_FC1 ? I_DIM * H_DIM : H_DIM * O_DIM);

    __shared__ __align__(16) __bf16 Bsl[BN * BSTR];
    __shared__ int sl_tok[IS_FC1 ? CAP : 1];
    __shared__ int sMe;

    const int tid = threadIdx.x;
    const int lane = tid & 63, w = tid >> 6;
    const int l15 = lane & 15, q = lane >> 4;

    if (IS_FC1 && w == 0) {
        int cnt = 0;
#pragma unroll
        for (int b = 0; b < 2; ++b) {
            int vals[16];
#pragma unroll
            for (int c = 0; c < 16; ++c)
                vals[c] = tok_e[(b * 16 + c) * 64 + lane];
#pragma unroll
            for (int c = 0; c < 16; ++c) {
                const int gidx = (b * 16 + c) * 64 + lane;
                const bool hit = (vals[c] == e);
                const unsigned long long mk = __ballot(hit);
                if (hit) {
                    const int pos = cnt + __popcll(mk & ((1ull << lane) - 1));
                    sl_tok[pos] = gidx >> 1;
                    if (blockIdx.x == 0) tok_slot[gidx] = off + pos;
                }
                cnt += __popcll(mk);
            }
        }
        if (lane == 0) {
            sMe = cnt;
            if (blockIdx.x == 0) counts[e] = cnt;
        }
    }
    const int MeG = IS_FC1 ? 0 : counts[e];

    auto stage_chunk = [&](int ch) {
        const int kb = k0 + ch * 256;
#pragma unroll
        for (int i = 0; i < (128 * C4N) / 512; ++i) {
            const int u = tid + 512 * i;
            const int p = u / C4N, c4 = u % C4N;
            const float* wp = W + (size_t)(kb + 2 * p) * NW + n0 + c4 * 4;
            float4 r0 = *(const float4*)wp;
            float4 r1 = *(const float4*)(wp + NW);
            const float* f0 = (const float*)&r0;
            const float* f1 = (const float*)&r1;
#pragma unroll
            for (int j = 0; j < 4; ++j) {
                bf16x2 pk;
                pk[0] = (__bf16)f0[j];
                pk[1] = (__bf16)f1[j];
                *(bf16x2*)&Bsl[(size_t)(c4 * 4 + j) * BSTR + ch * 256 + 2 * p] = pk;
            }
        }
    };

    stage_chunk(0);
    __syncthreads();
#pragma unroll
    for (int ch = 1; ch < NCH; ++ch) stage_chunk(ch);

    const int Me = IS_FC1 ? sMe : MeG;

    auto set_aptr = [&](int m0, const __bf16*& a0, const __bf16*& a1) {
        int mA = m0 + l15;      if (mA >= Me) mA = Me - 1;
        int mB = m0 + 16 + l15; if (mB >= Me) mB = Me - 1;
        if (IS_FC1) {
            a0 = A + (size_t)sl_tok[mA] * ASTR + q * 8;
            a1 = A + (size_t)sl_tok[mB] * ASTR + q * 8;
        } else {
            a0 = A + (size_t)(off + mA) * ASTR + k0 + q * 8;
            a1 = A + (size_t)(off + mB) * ASTR + k0 + q * 8;
        }
    };
    auto compute = [&](const __bf16* a0, const __bf16* a1,
                       f32x4 (&acc)[2][JN], int ks0, int ks1) {
#pragma unroll 4
        for (int ks = ks0; ks < ks1; ++ks) {
            bf16x8 af0 = *(const bf16x8*)(a0 + ks * 32);
            bf16x8 af1 = *(const bf16x8*)(a1 + ks * 32);
#pragma unroll
            for (int jj = 0; jj < JN; ++jj) {
                bf16x8 bf = *(const bf16x8*)
                    &Bsl[(size_t)(jj * 16 + l15) * BSTR + ks * 32 + q * 8];
                acc[0][jj] = MFMA16(af0, bf, acc[0][jj], 0, 0, 0);
                acc[1][jj] = MFMA16(af1, bf, acc[1][jj], 0, 0, 0);
            }
        }
    };
    auto epilogue = [&](int m0, f32x4 (&acc)[2][JN]) {
#pragma unroll
        for (int jj = 0; jj < JN; ++jj) {
            const int gn = n0 + jj * 16 + l15;
            if (IS_FC1) {
                const float bv = bias[e * H_DIM + gn];
#pragma unroll
                for (int i = 0; i < 2; ++i)
#pragma unroll
                    for (int r = 0; r < 4; ++r) {
                        int m = m0 + i * 16 + q * 4 + r;
                        if (m < Me) {
                            float v = acc[i][jj][r] + bv;
                            hb[(size_t)(off + m) * H_DIM + gn] =
                                (__bf16)fmaxf(v, 0.f);
                        }
                    }
            } else {
#pragma unroll
                for (int i = 0; i < 2; ++i)
#pragma unroll
                    for (int r = 0; r < 4; ++r) {
                        int m = m0 + i * 16 + q * 4 + r;
                        if (m < Me)
                            y2[((size_t)kc * (E_NUM * CAP) + off + m) * O_DIM + gn] =
                                acc[i][jj][r];
                    }
            }
        }
    };

    const bool act0 = (w * 32 < Me);
    int m0 = w * 32;
    f32x4 acc[2][JN] = {};
    const __bf16 *a0 = nullptr, *a1 = nullptr;
    if (act0) {
        set_aptr(m0, a0, a1);
        compute(a0, a1, acc, 0, 8);
    }
    __syncthreads();
    if (act0) {
        compute(a0, a1, acc, 8, KSPAN / 32);
        epilogue(m0, acc);
    }
    for (m0 = w * 32 + 256; m0 < Me; m0 += 256) {
        f32x4 acc2[2][JN] = {};
        set_aptr(m0, a0, a1);
        compute(a0, a1, acc2, 0, KSPAN / 32);
        epilogue(m0, acc2);
    }
}

__global__ __launch_bounds__(256) void combine_kernel(
    const float* __restrict__ y2, const float* __restrict__ b2,
    const int* __restrict__ tok_slot, const int* __restrict__ tok_e,
    const float* __restrict__ tok_w, float* __restrict__ out)
{
    const int idx = blockIdx.x * 256 + threadIdx.x;
    const int t = idx >> 7;
    const int c = (idx & 127) * 4;
    float4 sum = {0.f, 0.f, 0.f, 0.f};
#pragma unroll
    for (int k = 0; k < 2; ++k) {
        const int s = tok_slot[t * 2 + k];
        const int e = tok_e[t * 2 + k];
        const float wgt = tok_w[t * 2 + k];
        float4 a = *(const float4*)(b2 + (size_t)e * O_DIM + c);
#pragma unroll
        for (int kc = 0; kc < 2; ++kc) {
            float4 v = *(const float4*)
                (y2 + ((size_t)kc * (E_NUM * CAP) + s) * O_DIM + c);
            a.x += v.x; a.y += v.y; a.z += v.z; a.w += v.w;
        }
        sum.x += wgt * a.x; sum.y += wgt * a.y;
        sum.z += wgt * a.z; sum.w += wgt * a.w;
    }
    *(float4*)(out + (size_t)t * O_DIM + c) = sum;
}

// ===========================================================================
extern "C" void kernel_launch(void* const* d_in, const int* in_sizes, int n_in,
                              void* d_out, int out_size, void* d_ws, size_t ws_size,
                              hipStream_t stream)
{
    const float* x  = (const float*)d_in[0];
    const float* Wg = (const float*)d_in[1];
    const float* bg = (const float*)d_in[2];
    const float* W1 = (const float*)d_in[3];
    const float* b1 = (const float*)d_in[4];
    const float* W2 = (const float*)d_in[5];
    const float* b2 = (const float*)d_in[6];
    float* out = (float*)d_out;
    char* ws = (char*)d_ws;

    void* args[] = {(void*)&x, (void*)&Wg, (void*)&bg, (void*)&W1, (void*)&b1,
                    (void*)&W2, (void*)&b2, (void*)&out, (void*)&ws};
    hipError_t err = hipLaunchCooperativeKernel(
        (const void*)moe_fused, dim3(256), dim3(512), args, 0, stream);
    if (err == hipSuccess) return;

    // -------- fallback: R9 4-kernel path --------
    int*    counts   = (int*)(ws + WS_COUNTS);
    int*    tok_e    = (int*)(ws + WS_TOK_E);
    float*  tok_w    = (float*)(ws + WS_TOK_W);
    int*    tok_slot = (int*)(ws + WS_TOK_SLOT);
    __bf16* xb       = (__bf16*)(ws + WS_XB);
    __bf16* hb       = (__bf16*)(ws + WS_HB);
    float*  y2       = (float*)(ws + WS_Y2);

    gating_kernel<<<B_TOK / 4, 256, 0, stream>>>(x, Wg, bg, xb, tok_e, tok_w);
    moe_gemm<true><<<dim3(32, 1, 8), 512, 0, stream>>>(
        xb, W1, b1, counts, tok_e, tok_slot, hb, y2);
    moe_gemm<false><<<dim3(16, 2, 8), 512, 0, stream>>>(
        hb, W2, b2, counts, tok_e, tok_slot, hb, y2);
    combine_kernel<<<(B_TOK * O_DIM / 4) / 256, 256, 0, stream>>>(
        y2, b2, tok_slot, tok_e, tok_w, out);
}

// Round 3
// 195.941 us; speedup vs baseline: 1.3359x; 1.3359x over previous
//
#include <hip/hip_runtime.h>
#include <math.h>

// MoE top-2-of-8: B=1024, I=512, H=2048, O=512, E=8, K=2.
// R11: latency-bound fix (R10 counters: MfmaUtil 2.2%, VALUBusy 2.6%, occ 23%
// -> everything idle). Changes:
//  1) prep kernel transposes W1/W2 ONCE to bf16 [n][k] (W1T/W2T) at stream BW,
//     so both GEMMs read A and B as per-lane k-contiguous bf16x8 global loads
//     (m97-proven frag pattern) -- NO LDS staging, NO barriers in the hot loop.
//  2) all grids >=512 blocks x 256 thr (2+ blocks/CU, 8+ waves/CU) for TLP.
//  3) non-cooperative 4-kernel pipeline (fusion measured neutral).
// prep also does gating (blocks 0..255). fc1 rebuilds per-expert slot lists
// with the R9 wave-0 ballot scan (4KB LDS); fc2 kc=2 halves -> y2 partials;
// combine sums. MFMA 16x16x32 bf16, C/D layout col=l15,row=q*4+r (m89).

#define B_TOK 1024
#define I_DIM 512
#define H_DIM 2048
#define O_DIM 512
#define E_NUM 8
#define CAP   1024                       // per-expert slot capacity

#define WS_COUNTS   0                    // 8 ints (written by fc1 nx==0,my==0)
#define WS_TOK_E    64                   // [1024][2] int
#define WS_TOK_W    8256                 // [1024][2] float
#define WS_TOK_SLOT 16448                // [1024][2] int
#define WS_XB       65536                // [1024][512] bf16 = 1 MB
#define WS_W1T      1114112              // [8][2048][512] bf16 = 16 MB
#define WS_W2T      17891328             // [8][512][2048] bf16 = 16 MB
#define WS_HB       34668544             // [8*1024][2048] bf16 = 32 MB
#define WS_Y2       68222976             // [2][8192][512] f32 = 32 MB

typedef __attribute__((ext_vector_type(8))) __bf16 bf16x8;
typedef __attribute__((ext_vector_type(4))) __bf16 bf16x4;
typedef __attribute__((ext_vector_type(2))) __bf16 bf16x2;
typedef __attribute__((ext_vector_type(4))) float f32x4;

#define MFMA16 __builtin_amdgcn_mfma_f32_16x16x32_bf16

// ---------------------------------------------------------------------------
// prep: blocks 0..255 gate 4 tokens each (one per wave) + convert x->xb bf16;
// ALL 1024 blocks then transpose one 64k x 256n W-tile to bf16 [n][k].
// Tiles 0..511 = W1 (e=b>>6; kt=(b&63)>>3, nt=(b&63)&7);
// tiles 512..1023 = W2 (e=(b-512)>>6; kt=(t)>>1, nt=t&1).
__global__ __launch_bounds__(256) void prep_kernel(
    const float* __restrict__ x, const float* __restrict__ Wg,
    const float* __restrict__ bg, const float* __restrict__ W1f,
    const float* __restrict__ W2f,
    __bf16* __restrict__ xb, int* __restrict__ tok_e,
    float* __restrict__ tok_w,
    __bf16* __restrict__ W1T, __bf16* __restrict__ W2T)
{
    const int tid = threadIdx.x, lane = tid & 63, w = tid >> 6;
    const int b = blockIdx.x;

    // ---- gating (blocks 0..255, one token per wave) ----
    if (b < 256) {
        const int t = b * 4 + w;
        const float4* x4 = (const float4*)(x + (size_t)t * I_DIM);
        float4 va = x4[lane], vb = x4[lane + 64];
        bf16x4 oa, ob;
        oa[0] = (__bf16)va.x; oa[1] = (__bf16)va.y;
        oa[2] = (__bf16)va.z; oa[3] = (__bf16)va.w;
        ob[0] = (__bf16)vb.x; ob[1] = (__bf16)vb.y;
        ob[2] = (__bf16)vb.z; ob[3] = (__bf16)vb.w;
        *(bf16x4*)(xb + (size_t)t * I_DIM + lane * 4) = oa;
        *(bf16x4*)(xb + (size_t)t * I_DIM + 256 + lane * 4) = ob;

        float gacc[8];
#pragma unroll
        for (int e = 0; e < 8; ++e) gacc[e] = 0.f;
        float xv[8] = {va.x, va.y, va.z, va.w, vb.x, vb.y, vb.z, vb.w};
#pragma unroll
        for (int u = 0; u < 8; ++u) {
            int i = (u < 4) ? (lane * 4 + u) : (256 + lane * 4 + u - 4);
            const float4* wr = (const float4*)(Wg + (size_t)i * 8);
            float4 wa = wr[0], wb2 = wr[1];
            gacc[0] = fmaf(xv[u], wa.x, gacc[0]);
            gacc[1] = fmaf(xv[u], wa.y, gacc[1]);
            gacc[2] = fmaf(xv[u], wa.z, gacc[2]);
            gacc[3] = fmaf(xv[u], wa.w, gacc[3]);
            gacc[4] = fmaf(xv[u], wb2.x, gacc[4]);
            gacc[5] = fmaf(xv[u], wb2.y, gacc[5]);
            gacc[6] = fmaf(xv[u], wb2.z, gacc[6]);
            gacc[7] = fmaf(xv[u], wb2.w, gacc[7]);
        }
#pragma unroll
        for (int off = 32; off > 0; off >>= 1)
#pragma unroll
            for (int e = 0; e < 8; ++e)
                gacc[e] += __shfl_xor(gacc[e], off, 64);
        if (lane == 0) {
            float l[8];
#pragma unroll
            for (int e = 0; e < 8; ++e) l[e] = gacc[e] + bg[e];
            int E0 = 0;
            for (int e = 1; e < 8; ++e) if (l[e] > l[E0]) E0 = e;
            int E1 = (E0 == 0) ? 1 : 0;
            for (int e = 0; e < 8; ++e) {
                if (e == E0) continue;
                if (l[e] > l[E1]) E1 = e;
            }
            float w0 = 1.f / (1.f + expf(l[E1] - l[E0]));  // p0/(p0+p1)
            tok_e[t * 2]     = E0;
            tok_e[t * 2 + 1] = E1;
            tok_w[t * 2]     = w0;
            tok_w[t * 2 + 1] = 1.f - w0;
        }
    }

    // ---- transpose one 64k x 256n tile ----
    const float* src; __bf16* dst; int NWs, KT, k0, n0;
    if (b < 512) {
        const int e = b >> 6, t = b & 63;
        src = W1f + (size_t)e * I_DIM * H_DIM;
        dst = W1T + (size_t)e * H_DIM * I_DIM;
        NWs = H_DIM; KT = I_DIM;
        k0 = (t >> 3) * 64; n0 = (t & 7) * 256;
    } else {
        const int u = b - 512, e = u >> 6, t = u & 63;
        src = W2f + (size_t)e * H_DIM * O_DIM;
        dst = W2T + (size_t)e * O_DIM * H_DIM;
        NWs = O_DIM; KT = H_DIM;
        k0 = (t >> 1) * 64; n0 = (t & 1) * 256;
    }
    __shared__ uint32_t T[256 * 33];     // [n][k-pair] packed bf16x2, 33 KB
#pragma unroll
    for (int i = 0; i < 8; ++i) {        // 2048 read units / 256 thr
        const int u = tid + 256 * i;
        const int p = u >> 6, c4 = u & 63;      // k-pair, n-quad
        const float* wp = src + (size_t)(k0 + 2 * p) * NWs + n0 + c4 * 4;
        float4 r0 = *(const float4*)wp;
        float4 r1 = *(const float4*)(wp + NWs);
        const float* f0 = (const float*)&r0;
        const float* f1 = (const float*)&r1;
#pragma unroll
        for (int j = 0; j < 4; ++j) {
            bf16x2 pk;
            pk[0] = (__bf16)f0[j];
            pk[1] = (__bf16)f1[j];
            *(bf16x2*)&T[(c4 * 4 + j) * 33 + p] = pk;
        }
    }
    __syncthreads();
#pragma unroll
    for (int i = 0; i < 8; ++i) {        // 2048 write units (16B) / 256 thr
        const int v = tid + 256 * i;
        const int n = v >> 3, s = v & 7;
        uint4 d;
        d.x = T[n * 33 + s * 4 + 0];
        d.y = T[n * 33 + s * 4 + 1];
        d.z = T[n * 33 + s * 4 + 2];
        d.w = T[n * 33 + s * 4 + 3];
        *(uint4*)(dst + (size_t)(n0 + n) * KT + k0 + s * 8) = d;
    }
}

// ---------------------------------------------------------------------------
// fc1: grid (32 nx, 2 my, 8 e) = 512 blocks x 256 thr (4 waves).
// Wave strip = 32 m-rows, n-panel 64 (JN=4). No LDS W; B-frags stream W1T.
__global__ __launch_bounds__(256) void fc1_kernel(
    const __bf16* __restrict__ xb, const __bf16* __restrict__ W1T,
    const float* __restrict__ b1, const int* __restrict__ tok_e,
    int* __restrict__ counts, int* __restrict__ tok_slot,
    __bf16* __restrict__ hb)
{
    const int tid = threadIdx.x, lane = tid & 63, w = tid >> 6;
    const int l15 = lane & 15, q = lane >> 4;
    const int e = blockIdx.z, my = blockIdx.y, nx = blockIdx.x;
    const int n0 = nx * 64;

    __shared__ int sl[CAP];
    __shared__ int sMe;

    // wave-0 ballot scan: deterministic token-order slot list for expert e.
    if (w == 0) {
        int cnt = 0;
#pragma unroll
        for (int bb = 0; bb < 2; ++bb) {
            int vals[16];
#pragma unroll
            for (int c = 0; c < 16; ++c)
                vals[c] = tok_e[(bb * 16 + c) * 64 + lane];
#pragma unroll
            for (int c = 0; c < 16; ++c) {
                const int gidx = (bb * 16 + c) * 64 + lane;
                const bool hit = (vals[c] == e);
                const unsigned long long mk = __ballot(hit);
                if (hit) {
                    const int pos = cnt + __popcll(mk & ((1ull << lane) - 1));
                    sl[pos] = gidx >> 1;
                    if (nx == 0 && my == 0) tok_slot[gidx] = e * CAP + pos;
                }
                cnt += __popcll(mk);
            }
        }
        if (lane == 0) {
            sMe = cnt;
            if (nx == 0 && my == 0) counts[e] = cnt;
        }
    }
    __syncthreads();
    const int Me = sMe;

    const __bf16* Wt  = W1T + (size_t)e * H_DIM * I_DIM;
    const __bf16* bp0 = Wt + (size_t)(n0 + l15) * I_DIM + q * 8;

    for (int m0 = my * 128 + w * 32; m0 < Me; m0 += 256) {
        int mA = m0 + l15;      if (mA >= Me) mA = Me - 1;
        int mB = m0 + 16 + l15; if (mB >= Me) mB = Me - 1;
        const __bf16* a0 = xb + (size_t)sl[mA] * I_DIM + q * 8;
        const __bf16* a1 = xb + (size_t)sl[mB] * I_DIM + q * 8;
        f32x4 acc[2][4] = {};
#pragma unroll 4
        for (int ks = 0; ks < 16; ++ks) {
            bf16x8 af0 = *(const bf16x8*)(a0 + ks * 32);
            bf16x8 af1 = *(const bf16x8*)(a1 + ks * 32);
#pragma unroll
            for (int jj = 0; jj < 4; ++jj) {
                bf16x8 bf = *(const bf16x8*)(bp0 + (size_t)jj * 16 * I_DIM + ks * 32);
                acc[0][jj] = MFMA16(af0, bf, acc[0][jj], 0, 0, 0);
                acc[1][jj] = MFMA16(af1, bf, acc[1][jj], 0, 0, 0);
            }
        }
#pragma unroll
        for (int jj = 0; jj < 4; ++jj) {
            const int gn = n0 + jj * 16 + l15;
            const float bv = b1[e * H_DIM + gn];
#pragma unroll
            for (int i = 0; i < 2; ++i)
#pragma unroll
                for (int r = 0; r < 4; ++r) {
                    int m = m0 + i * 16 + q * 4 + r;
                    if (m < Me) {
                        float v = acc[i][jj][r] + bv;
                        hb[(size_t)(e * CAP + m) * H_DIM + gn] =
                            (__bf16)fmaxf(v, 0.f);
                    }
                }
        }
    }
}

// ---------------------------------------------------------------------------
// fc2: grid (16 nx, 4 (my|kc<<1), 8 e) = 512 blocks x 256 thr (4 waves).
// Wave strip = 32 m-rows, n-panel 32 (JN=2), K-half 1024 -> y2 partials.
__global__ __launch_bounds__(256) void fc2_kernel(
    const __bf16* __restrict__ hb, const __bf16* __restrict__ W2T,
    const int* __restrict__ counts, float* __restrict__ y2)
{
    const int tid = threadIdx.x, lane = tid & 63, w = tid >> 6;
    const int l15 = lane & 15, q = lane >> 4;
    const int e = blockIdx.z;
    const int my = blockIdx.y & 1, kc = blockIdx.y >> 1;
    const int n0 = blockIdx.x * 32;
    const int k0 = kc * 1024;

    const int Me = counts[e];
    if (Me == 0) return;

    const __bf16* Wt  = W2T + (size_t)e * O_DIM * H_DIM;
    const __bf16* bp0 = Wt + (size_t)(n0 + l15) * H_DIM + k0 + q * 8;

    for (int m0 = my * 128 + w * 32; m0 < Me; m0 += 256) {
        int mA = m0 + l15;      if (mA >= Me) mA = Me - 1;
        int mB = m0 + 16 + l15; if (mB >= Me) mB = Me - 1;
        const __bf16* a0 = hb + (size_t)(e * CAP + mA) * H_DIM + k0 + q * 8;
        const __bf16* a1 = hb + (size_t)(e * CAP + mB) * H_DIM + k0 + q * 8;
        f32x4 acc[2][2] = {};
#pragma unroll 4
        for (int ks = 0; ks < 32; ++ks) {
            bf16x8 af0 = *(const bf16x8*)(a0 + ks * 32);
            bf16x8 af1 = *(const bf16x8*)(a1 + ks * 32);
#pragma unroll
            for (int jj = 0; jj < 2; ++jj) {
                bf16x8 bf = *(const bf16x8*)(bp0 + (size_t)jj * 16 * H_DIM + ks * 32);
                acc[0][jj] = MFMA16(af0, bf, acc[0][jj], 0, 0, 0);
                acc[1][jj] = MFMA16(af1, bf, acc[1][jj], 0, 0, 0);
            }
        }
#pragma unroll
        for (int jj = 0; jj < 2; ++jj) {
            const int gn = n0 + jj * 16 + l15;
#pragma unroll
            for (int i = 0; i < 2; ++i)
#pragma unroll
                for (int r = 0; r < 4; ++r) {
                    int m = m0 + i * 16 + q * 4 + r;
                    if (m < Me)
                        y2[((size_t)kc * (E_NUM * CAP) + e * CAP + m) * O_DIM + gn] =
                            acc[i][jj][r];
                }
        }
    }
}

// ---------------------------------------------------------------------------
// out[t][c] = sum_k w_k * (b2[e_k][c] + sum_kc y2[kc][slot_k][c])
__global__ __launch_bounds__(256) void combine_kernel(
    const float* __restrict__ y2, const float* __restrict__ b2,
    const int* __restrict__ tok_slot, const int* __restrict__ tok_e,
    const float* __restrict__ tok_w, float* __restrict__ out)
{
    const int idx = blockIdx.x * 256 + threadIdx.x;   // B*O/4
    const int t = idx >> 7;
    const int c = (idx & 127) * 4;
    float4 sum = {0.f, 0.f, 0.f, 0.f};
#pragma unroll
    for (int k = 0; k < 2; ++k) {
        const int s = tok_slot[t * 2 + k];
        const int e = tok_e[t * 2 + k];
        const float wgt = tok_w[t * 2 + k];
        float4 a = *(const float4*)(b2 + (size_t)e * O_DIM + c);
#pragma unroll
        for (int kc = 0; kc < 2; ++kc) {
            float4 v = *(const float4*)
                (y2 + ((size_t)kc * (E_NUM * CAP) + s) * O_DIM + c);
            a.x += v.x; a.y += v.y; a.z += v.z; a.w += v.w;
        }
        sum.x += wgt * a.x; sum.y += wgt * a.y;
        sum.z += wgt * a.z; sum.w += wgt * a.w;
    }
    *(float4*)(out + (size_t)t * O_DIM + c) = sum;
}

// ===========================================================================
extern "C" void kernel_launch(void* const* d_in, const int* in_sizes, int n_in,
                              void* d_out, int out_size, void* d_ws, size_t ws_size,
                              hipStream_t stream)
{
    const float* x  = (const float*)d_in[0];
    const float* Wg = (const float*)d_in[1];
    const float* bg = (const float*)d_in[2];
    const float* W1 = (const float*)d_in[3];
    const float* b1 = (const float*)d_in[4];
    const float* W2 = (const float*)d_in[5];
    const float* b2 = (const float*)d_in[6];
    float* out = (float*)d_out;
    char* ws = (char*)d_ws;

    int*    counts   = (int*)(ws + WS_COUNTS);
    int*    tok_e    = (int*)(ws + WS_TOK_E);
    float*  tok_w    = (float*)(ws + WS_TOK_W);
    int*    tok_slot = (int*)(ws + WS_TOK_SLOT);
    __bf16* xb       = (__bf16*)(ws + WS_XB);
    __bf16* W1T      = (__bf16*)(ws + WS_W1T);
    __bf16* W2T      = (__bf16*)(ws + WS_W2T);
    __bf16* hb       = (__bf16*)(ws + WS_HB);
    float*  y2       = (float*)(ws + WS_Y2);

    // gating + W-transpose/convert (1024 blocks: 96 MB streamed, ~4 blocks/CU)
    prep_kernel<<<1024, 256, 0, stream>>>(x, Wg, bg, W1, W2,
                                          xb, tok_e, tok_w, W1T, W2T);
    // fc1: 32 n-panels x 2 m-halves x 8 experts = 512 blocks (2/CU)
    fc1_kernel<<<dim3(32, 2, 8), 256, 0, stream>>>(
        xb, W1T, b1, tok_e, counts, tok_slot, hb);
    // fc2: 16 n-panels x (2 my x 2 kc) x 8 experts = 512 blocks (2/CU)
    fc2_kernel<<<dim3(16, 4, 8), 256, 0, stream>>>(hb, W2T, counts, y2);
    combine_kernel<<<(B_TOK * O_DIM / 4) / 256, 256, 0, stream>>>(
        y2, b2, tok_slot, tok_e, tok_w, out);
}